// Round 1
// baseline (1067.278 us; speedup 1.0000x reference)
//
#include <hip/hip_runtime.h>
#include <stdint.h>

typedef __bf16 bf16_t;
typedef bf16_t bf16x8 __attribute__((ext_vector_type(8)));
typedef float floatx4 __attribute__((ext_vector_type(4)));

__device__ __forceinline__ ushort f2bf(float f) {
  uint u = __float_as_uint(f);
  u += 0x7FFFu + ((u >> 16) & 1u);   // RNE; inputs finite/normal
  return (ushort)(u >> 16);
}
__device__ __forceinline__ float bf2f(ushort h) {
  return __uint_as_float(((uint)h) << 16);
}

// async 16B global->LDS DMA. LDS dest = wave-uniform base + lane*16.
__device__ __forceinline__ void async_cp16(const ushort* g, ushort* l) {
  __builtin_amdgcn_global_load_lds(
      (const __attribute__((address_space(1))) uint32_t*)g,
      (__attribute__((address_space(3))) uint32_t*)l, 16, 0, 0);
}

// ---------------- fp32 -> bf16 convert ----------------
__global__ __launch_bounds__(256) void cvt_f32_bf16(const float* __restrict__ in,
                                                    ushort* __restrict__ out,
                                                    long long n) {
  long long i = (((long long)blockIdx.x) * 256 + threadIdx.x) * 4;
  if (i + 3 < n) {
    float4 f = *(const float4*)(in + i);
    ushort4 o = make_ushort4(f2bf(f.x), f2bf(f.y), f2bf(f.z), f2bf(f.w));
    *(ushort4*)(out + i) = o;
  }
}

// ---- pack Wq/Wk/Wv (fp32) -> Wp[4][1536][512] bf16 (rows: Q,K,V stacked) ----
__global__ __launch_bounds__(256) void pack_w(const float* __restrict__ Wq,
                                              const float* __restrict__ Wk,
                                              const float* __restrict__ Wv,
                                              ushort* __restrict__ Wp) {
  long long t4 = (((long long)blockIdx.x) * 256 + threadIdx.x) * 4;  // < 4*1536*512
  const int k = (int)(t4 & 511);
  const int jr = (int)(t4 >> 9);       // 0..6143
  const int pi = jr / 1536;
  const int j = jr - pi * 1536;
  const int type = j >> 9;             // 0=Q 1=K 2=V
  const int jj = j & 511;
  const float* src = (type == 0 ? Wq : type == 1 ? Wk : Wv) +
                     ((long long)(pi * 512 + jj) << 9) + k;
  float4 f = *(const float4*)src;
  ushort4 o = make_ushort4(f2bf(f.x), f2bf(f.y), f2bf(f.z), f2bf(f.w));
  *(ushort4*)(Wp + t4) = o;
}

__global__ __launch_bounds__(256) void pack_b(const float* __restrict__ bq,
                                              const float* __restrict__ bk,
                                              const float* __restrict__ bv,
                                              float* __restrict__ Bp) {
  const int i = blockIdx.x * 256 + threadIdx.x;  // < 6144
  const int pi = i / 1536;
  const int j = i - pi * 1536;
  const int type = j >> 9;
  const int jj = j & 511;
  Bp[i] = (type == 0 ? bq : type == 1 ? bk : bv)[pi * 512 + jj];
}

// =====================================================================
// 256x256 8-phase BT-form bf16 MFMA GEMM (learn_hip m201 template class).
// C[m,n] = sum_k A[m,k]*B[n,k]; both operands k-contiguous.
// 512 threads = 8 waves (2M x 4N); per-wave output 128x64.
// LDS 128 KiB: [op A/B][dbuf][half 128rows][128*64] bf16, linear layout
// for global_load_lds; XOR swizzle (chunk ^= row&7, 16B chunks) folded
// into the per-lane GLOBAL source address; same XOR applied on ds_read.
// Per K-tile: 4 phases {ds_read subtile | stage 1 half-tile | barrier |
// lgkmcnt(0) | setprio(1) | 16 MFMA | setprio(0) | barrier}.
// Counted vmcnt(6) once per K-tile (3 half-tiles stay in flight);
// tail groups drain vmcnt(0). Staging region order B0,B1,A0,A1 is
// race-free vs the uniform read schedule (all B reads in ph1; A-half
// reads complete by ph3); sched_barrier(0) fences pin stages in-phase.
// =====================================================================

enum { EP_BIAS = 0, EP_KV = 1, EP_SCALE = 2, EP_ACC = 3, EP_FINAL = 4 };

#define SBAR0 __builtin_amdgcn_sched_barrier(0)

#define PH_MID                                        \
  SBAR0;                                              \
  __builtin_amdgcn_s_barrier();                       \
  asm volatile("s_waitcnt lgkmcnt(0)" ::: "memory");  \
  SBAR0;                                              \
  __builtin_amdgcn_s_setprio(1);

#define PH_END                                        \
  __builtin_amdgcn_s_setprio(0);                      \
  SBAR0;                                              \
  __builtin_amdgcn_s_barrier();                       \
  SBAR0;

template <int MODE, bool ACCUM>
__global__ __launch_bounds__(512, 2)
void gemm256(const ushort* __restrict__ A, const ushort* __restrict__ B,
             void* __restrict__ C, void* __restrict__ C2,
             const float* __restrict__ aux,
             int M, int N, int K, int lda, int ldb, int ldc,
             long long sA, long long sB, long long sC, long long sAux,
             float scale) {
  __shared__ __align__(16) ushort lds[2][2][2][8192];  // [A/B][buf][half][128*64]
  const int b = blockIdx.z;
  const ushort* Ab = A + (long long)b * sA;
  const ushort* Bb = B + (long long)b * sB;
  const int m0 = blockIdx.y * 256;
  const int n0 = blockIdx.x * 256;
  const int tid = threadIdx.x;
  const int lane = tid & 63;
  const int w = tid >> 6;        // wave 0..7
  const int wm = w >> 2;         // 0..1  (M half)
  const int wn = w & 3;          // 0..3  (N quarter)
  const int wnh = wn >> 1;       // B half
  const int l15 = lane & 15;
  const int quad = lane >> 4;
  const int x7 = l15 & 7;
  const int ck0 = ((quad ^ x7) << 3);  // swizzled chunk offset, ks=0 (ushorts)
  const int ck1 = ck0 ^ 32;            // ks=1
  const int bofs = ((((wn & 1) << 6) + l15) << 6);

  // staging geometry: thread covers 16B chunks (w*2+i)*64+lane of a half-tile
  int sa[2], sb[2], wo[2];
#pragma unroll
  for (int i = 0; i < 2; ++i) {
    const int off16 = (((w << 1) + i) << 6) | lane;  // 0..1023
    const int r = off16 >> 3;                        // row in half (0..127)
    const int c = ((off16 & 7) ^ (r & 7)) << 3;      // swizzled global chunk
    sa[i] = r * lda + c;
    sb[i] = r * ldb + c;
    wo[i] = ((w << 1) + i) << 9;                     // LDS ushort offset
  }
  const int sA0 = sa[0], sA1 = sa[1], sB0 = sb[0], sB1 = sb[1];
  const int wo0 = wo[0], wo1 = wo[1];

  auto stageA = [&](int tile, int half) {
    const ushort* g = Ab + (long long)(m0 + (half << 7)) * lda + (tile << 6);
    ushort* rb = &lds[0][tile & 1][half][0];
    async_cp16(g + sA0, rb + wo0);
    async_cp16(g + sA1, rb + wo1);
  };
  auto stageB = [&](int tile, int half) {
    const ushort* g = Bb + (long long)(n0 + (half << 7)) * ldb + (tile << 6);
    ushort* rb = &lds[1][tile & 1][half][0];
    async_cp16(g + sB0, rb + wo0);
    async_cp16(g + sB1, rb + wo1);
  };

  floatx4 acc[8][4];
#pragma unroll
  for (int i = 0; i < 8; ++i)
#pragma unroll
    for (int j = 0; j < 4; ++j)
#pragma unroll
      for (int r = 0; r < 4; ++r) acc[i][j][r] = 0.f;

  const int nt = K >> 6;  // K-tiles (>=2 at all call sites)

  // prologue: tile0 {B0,B1,A0,A1} + tile1 {B0,B1,A0}; SBAR0 keeps FIFO order
  stageB(0, 0); SBAR0; stageB(0, 1); SBAR0; stageA(0, 0); SBAR0; stageA(0, 1); SBAR0;
  stageB(1, 0); SBAR0; stageB(1, 1); SBAR0; stageA(1, 0); SBAR0;
  asm volatile("s_waitcnt vmcnt(6)" ::: "memory");  // tile0's 4 half-tiles landed
  SBAR0;
  __builtin_amdgcn_s_barrier();
  SBAR0;

  bf16x8 af[8], bfr[8];
  for (int kt = 0; kt < nt; ++kt) {
    const int bu = kt & 1;
    const ushort* As0 = &lds[0][bu][wm][0] + (l15 << 6);
    const ushort* Bs0 = &lds[1][bu][wnh][0] + bofs;

    // ---- phase 1: read A(lo,ks0)+B(all 8); stage A1(kt+1); mfma lo x ks0
#pragma unroll
    for (int i = 0; i < 4; ++i) af[i] = *(const bf16x8*)(As0 + i * 1024 + ck0);
#pragma unroll
    for (int i = 0; i < 4; ++i) bfr[i] = *(const bf16x8*)(Bs0 + i * 1024 + ck0);
#pragma unroll
    for (int i = 0; i < 4; ++i) bfr[4 + i] = *(const bf16x8*)(Bs0 + i * 1024 + ck1);
    if (kt + 1 < nt) stageA(kt + 1, 1);
    PH_MID
#pragma unroll
    for (int mi = 0; mi < 4; ++mi)
#pragma unroll
      for (int ni = 0; ni < 4; ++ni)
        acc[mi][ni] = __builtin_amdgcn_mfma_f32_16x16x32_bf16(
            af[mi], bfr[ni], acc[mi][ni], 0, 0, 0);
    PH_END

    // ---- phase 2: read A(lo,ks1)->af[4..7], A(hi,ks0)->af[0..3]; stage B0(kt+2)
#pragma unroll
    for (int i = 0; i < 4; ++i) af[4 + i] = *(const bf16x8*)(As0 + i * 1024 + ck1);
#pragma unroll
    for (int i = 0; i < 4; ++i) af[i] = *(const bf16x8*)(As0 + (4 + i) * 1024 + ck0);
    if (kt + 2 < nt) stageB(kt + 2, 0);
    PH_MID
#pragma unroll
    for (int mi = 0; mi < 4; ++mi)
#pragma unroll
      for (int ni = 0; ni < 4; ++ni)
        acc[mi][ni] = __builtin_amdgcn_mfma_f32_16x16x32_bf16(
            af[4 + mi], bfr[4 + ni], acc[mi][ni], 0, 0, 0);
    PH_END

    // ---- phase 3: read A(hi,ks1)->af[4..7]; stage B1(kt+2); mfma hi x ks0
#pragma unroll
    for (int i = 0; i < 4; ++i) af[4 + i] = *(const bf16x8*)(As0 + (4 + i) * 1024 + ck1);
    if (kt + 2 < nt) stageB(kt + 2, 1);
    PH_MID
#pragma unroll
    for (int mi = 0; mi < 4; ++mi)
#pragma unroll
      for (int ni = 0; ni < 4; ++ni)
        acc[4 + mi][ni] = __builtin_amdgcn_mfma_f32_16x16x32_bf16(
            af[mi], bfr[ni], acc[4 + mi][ni], 0, 0, 0);
    PH_END

    // ---- phase 4: stage A0(kt+2); mfma hi x ks1; counted vmcnt; barrier
    if (kt + 2 < nt) stageA(kt + 2, 0);
    PH_MID
#pragma unroll
    for (int mi = 0; mi < 4; ++mi)
#pragma unroll
      for (int ni = 0; ni < 4; ++ni)
        acc[4 + mi][ni] = __builtin_amdgcn_mfma_f32_16x16x32_bf16(
            af[4 + mi], bfr[4 + ni], acc[4 + mi][ni], 0, 0, 0);
    __builtin_amdgcn_s_setprio(0);
    SBAR0;
    if (kt + 2 < nt) {
      asm volatile("s_waitcnt vmcnt(6)" ::: "memory");  // tile kt+1 landed
    } else if (kt + 1 < nt) {
      asm volatile("s_waitcnt vmcnt(0)" ::: "memory");  // tail drain
    }
    SBAR0;
    __builtin_amdgcn_s_barrier();
    SBAR0;
  }

  // ---------------- epilogue ----------------
#pragma unroll
  for (int mi = 0; mi < 8; ++mi) {
#pragma unroll
    for (int ni = 0; ni < 4; ++ni) {
      const int gm0 = m0 + (wm << 7) + mi * 16 + (quad << 2);
      const int gn = n0 + (wn << 6) + ni * 16 + l15;
      if (MODE == EP_KV) {
        const float bias = aux[gn];
        if (gn < 512) {  // K half: normal layout (wave-uniform branch)
#pragma unroll
          for (int r = 0; r < 4; r++)
            ((ushort*)C)[(long long)(gm0 + r) * ldc + gn] =
                f2bf(acc[mi][ni][r] + bias);
        } else {  // V half: write transposed Vt[b][gn-512][token]
          const int b2 = gm0 >> 11;
          const int gmL = gm0 & 2047;
          ushort4 o;
          o.x = f2bf(acc[mi][ni][0] + bias);
          o.y = f2bf(acc[mi][ni][1] + bias);
          o.z = f2bf(acc[mi][ni][2] + bias);
          o.w = f2bf(acc[mi][ni][3] + bias);
          *(ushort4*)((ushort*)C2 + (long long)b2 * (512 * 2048) +
                      (long long)(gn - 512) * 2048 + gmL) = o;
        }
      } else {
        float bias = 0.f;
        if (MODE == EP_BIAS) bias = aux[gn];
#pragma unroll
        for (int r = 0; r < 4; r++) {
          const int gm = gm0 + r;
          const long long off = (long long)b * sC + (long long)gm * ldc + gn;
          float v = acc[mi][ni][r];
          if (MODE == EP_BIAS) {
            ((ushort*)C)[off] = f2bf(v + bias);
          } else if (MODE == EP_SCALE) {
            ((ushort*)C)[off] = f2bf(v * scale);
          } else if (MODE == EP_ACC) {
            if (ACCUM) v += bf2f(((ushort*)C)[off]);
            ((ushort*)C)[off] = f2bf(v);
          } else {  // EP_FINAL
            v += aux[(long long)b * sAux + (long long)gm * N + gn];
            ((float*)C)[off] = v;
          }
        }
      }
    }
  }
}

// ---------------- row softmax over 2048 bf16, in place ----------------
__global__ __launch_bounds__(256) void softmax_rows(ushort* __restrict__ S) {
  const long long row = blockIdx.x;
  ushort* p = S + (row << 11);
  const int t = threadIdx.x;
  const int lane = t & 63;
  const int w = t >> 6;

  uint4 raw = *(const uint4*)(p + (t << 3));
  const ushort* rs = (const ushort*)&raw;
  float v[8];
  for (int i = 0; i < 8; i++) v[i] = bf2f(rs[i]);

  float mx = v[0];
  for (int i = 1; i < 8; i++) mx = fmaxf(mx, v[i]);
  for (int off = 32; off; off >>= 1) mx = fmaxf(mx, __shfl_xor(mx, off, 64));
  __shared__ float redm[4];
  __shared__ float reds[4];
  if (lane == 0) redm[w] = mx;
  __syncthreads();
  mx = fmaxf(fmaxf(redm[0], redm[1]), fmaxf(redm[2], redm[3]));

  float s = 0.f;
  for (int i = 0; i < 8; i++) {
    v[i] = __expf(v[i] - mx);
    s += v[i];
  }
  for (int off = 32; off; off >>= 1) s += __shfl_xor(s, off, 64);
  if (lane == 0) reds[w] = s;
  __syncthreads();
  s = (reds[0] + reds[1]) + (reds[2] + reds[3]);
  const float inv = 1.0f / s;

  ushort o[8];
  for (int i = 0; i < 8; i++) o[i] = f2bf(v[i] * inv);
  *(uint4*)(p + (t << 3)) = *(const uint4*)o;
}

// ---------------- orchestration ----------------
extern "C" void kernel_launch(void* const* d_in, const int* in_sizes, int n_in,
                              void* d_out, int out_size, void* d_ws, size_t ws_size,
                              hipStream_t stream) {
  const float* Itime = (const float*)d_in[0];
  const float* Ispace = (const float*)d_in[1];
  const float* x0 = (const float*)d_in[2];
  const float* Wq = (const float*)d_in[3];
  const float* bq = (const float*)d_in[4];
  const float* Wk = (const float*)d_in[5];
  const float* bk = (const float*)d_in[6];
  const float* Wv = (const float*)d_in[7];
  const float* bv = (const float*)d_in[8];
  float* out = (float*)d_out;

  const long long SZX = 8388608;        // 8*2048*512
  const long long SZWP = 4LL * 1536 * 512;
  const long long SZS = 33554432;       // 8*2048*2048

  ushort* p = (ushort*)d_ws;
  ushort* Tb = p;   p += SZX;    // Itime bf16
  ushort* Sb = p;   p += SZX;    // Ispace bf16
  ushort* Wp = p;   p += SZWP;   // packed [4][1536][512] (Q,K,V rows)
  ushort* Qb = p;   p += SZX;    // Q proj [16384][512]
  ushort* Kb = p;   p += SZX;    // K proj [16384][512]
  ushort* Vt = p;   p += SZX;    // V^T [8][512][2048]
  ushort* Abf = p;  p += SZX;    // FTT + FTS
  ushort* Cbf = p;  p += SZX;    // FSS + FST
  ushort* Sc = p;   p += SZS;    // scores / probs (bf16)
  float* Bp = (float*)p;         // packed biases [4][1536] fp32 (24 KB)
  // total ws use ≈ 190.9 MB

  const dim3 blk(256);
  const dim3 blk2(512);
  cvt_f32_bf16<<<dim3(8192), blk, 0, stream>>>(Itime, Tb, SZX);
  cvt_f32_bf16<<<dim3(8192), blk, 0, stream>>>(Ispace, Sb, SZX);
  pack_w<<<dim3(3072), blk, 0, stream>>>(Wq, Wk, Wv, Wp);
  pack_b<<<dim3(24), blk, 0, stream>>>(bq, bk, bv, Bp);

  const float scale = 0.04419417382415922f;  // 1/sqrt(512)

  auto attn = [&](const ushort* qs, const ushort* kvs, int pi,
                  ushort* dest, bool accum) {
    const ushort* Wqi = Wp + (long long)pi * 1536 * 512;
    const ushort* Wkvi = Wqi + 512 * 512;
    const float* Bqi = Bp + pi * 1536;
    // Q projection: [16384,512] = qs(16384x512) . WqT
    gemm256<EP_BIAS, false><<<dim3(2, 64, 1), blk2, 0, stream>>>(
        qs, Wqi, Qb, nullptr, Bqi, 16384, 512, 512, 512, 512, 512,
        0, 0, 0, 0, 0.f);
    // K+V fused projection: K -> Kb (normal), V -> Vt (transposed per batch)
    gemm256<EP_KV, false><<<dim3(4, 64, 1), blk2, 0, stream>>>(
        kvs, Wkvi, Kb, Vt, Bqi + 512, 16384, 1024, 512, 512, 512, 512,
        0, 0, 0, 0, 0.f);
    // scores: S = scale * Q K^T (per batch 2048x2048)
    gemm256<EP_SCALE, false><<<dim3(8, 8, 8), blk2, 0, stream>>>(
        Qb, Kb, Sc, nullptr, nullptr, 2048, 2048, 512, 512, 512, 2048,
        1048576, 1048576, 4194304, 0, scale);
    softmax_rows<<<dim3(16384), blk, 0, stream>>>(Sc);
    // O (+)= P V : per batch M=2048, N=512, K=2048; B operand = Vt rows
    if (accum)
      gemm256<EP_ACC, true><<<dim3(2, 8, 8), blk2, 0, stream>>>(
          Sc, Vt, dest, nullptr, nullptr, 2048, 512, 2048, 2048, 2048, 512,
          4194304, 1048576, 1048576, 0, 0.f);
    else
      gemm256<EP_ACC, false><<<dim3(2, 8, 8), blk2, 0, stream>>>(
          Sc, Vt, dest, nullptr, nullptr, 2048, 512, 2048, 2048, 2048, 512,
          4194304, 1048576, 1048576, 0, 0.f);
  };

  attn(Tb, Tb, 0, Abf, false);   // FTT
  attn(Tb, Sb, 2, Abf, true);    // + FTS
  attn(Sb, Sb, 1, Cbf, false);   // FSS
  attn(Sb, Tb, 3, Cbf, true);    // + FST

  // out = Abf . Cbf^T + x_origin (fp32)
  gemm256<EP_FINAL, false><<<dim3(8, 8, 8), blk2, 0, stream>>>(
      Abf, Cbf, out, nullptr, x0, 2048, 2048, 512, 512, 512, 2048,
      1048576, 1048576, 4194304, 4194304, 0.f);
}

// Round 2
// 1009.486 us; speedup vs baseline: 1.0572x; 1.0572x over previous
//
#include <hip/hip_runtime.h>
#include <stdint.h>

typedef __bf16 bf16_t;
typedef bf16_t bf16x8 __attribute__((ext_vector_type(8)));
typedef float floatx4 __attribute__((ext_vector_type(4)));

__device__ __forceinline__ ushort f2bf(float f) {
  uint u = __float_as_uint(f);
  u += 0x7FFFu + ((u >> 16) & 1u);   // RNE; inputs finite/normal
  return (ushort)(u >> 16);
}
__device__ __forceinline__ float bf2f(ushort h) {
  return __uint_as_float(((uint)h) << 16);
}

// async 16B global->LDS DMA. LDS dest = wave-uniform base + lane*16.
__device__ __forceinline__ void async_cp16(const ushort* g, ushort* l) {
  __builtin_amdgcn_global_load_lds(
      (const __attribute__((address_space(1))) uint32_t*)g,
      (__attribute__((address_space(3))) uint32_t*)l, 16, 0, 0);
}

// ---------------- fp32 -> bf16 convert ----------------
__global__ __launch_bounds__(256) void cvt_f32_bf16(const float* __restrict__ in,
                                                    ushort* __restrict__ out,
                                                    long long n) {
  long long i = (((long long)blockIdx.x) * 256 + threadIdx.x) * 4;
  if (i + 3 < n) {
    float4 f = *(const float4*)(in + i);
    ushort4 o = make_ushort4(f2bf(f.x), f2bf(f.y), f2bf(f.z), f2bf(f.w));
    *(ushort4*)(out + i) = o;
  }
}

// ---- pack Wq/Wk/Wv (fp32) -> Wp[4][1536][512] bf16 (rows: Q,K,V stacked) ----
__global__ __launch_bounds__(256) void pack_w(const float* __restrict__ Wq,
                                              const float* __restrict__ Wk,
                                              const float* __restrict__ Wv,
                                              ushort* __restrict__ Wp) {
  long long t4 = (((long long)blockIdx.x) * 256 + threadIdx.x) * 4;  // < 4*1536*512
  const int k = (int)(t4 & 511);
  const int jr = (int)(t4 >> 9);       // 0..6143
  const int pi = jr / 1536;
  const int j = jr - pi * 1536;
  const int type = j >> 9;             // 0=Q 1=K 2=V
  const int jj = j & 511;
  const float* src = (type == 0 ? Wq : type == 1 ? Wk : Wv) +
                     ((long long)(pi * 512 + jj) << 9) + k;
  float4 f = *(const float4*)src;
  ushort4 o = make_ushort4(f2bf(f.x), f2bf(f.y), f2bf(f.z), f2bf(f.w));
  *(ushort4*)(Wp + t4) = o;
}

__global__ __launch_bounds__(256) void pack_b(const float* __restrict__ bq,
                                              const float* __restrict__ bk,
                                              const float* __restrict__ bv,
                                              float* __restrict__ Bp) {
  const int i = blockIdx.x * 256 + threadIdx.x;  // < 6144
  const int pi = i / 1536;
  const int j = i - pi * 1536;
  const int type = j >> 9;
  const int jj = j & 511;
  Bp[i] = (type == 0 ? bq : type == 1 ? bk : bv)[pi * 512 + jj];
}

// ---------------- BT-form bf16 MFMA GEMM ----------------
// C[m,n] = sum_k A[m,k]*B[n,k]; both operands k-contiguous (lda/ldb strides).
// BK=64. 128x128 tile, 256 threads (4 waves 2x2), 2 blocks/CU.
// T3-minimum double-buffered K-loop: stage tile kt+1 into buf^1 (async
// global_load_lds, issued BEFORE current tile's ds_read+MFMA), then ONE
// __syncthreads() per tile (its implicit vmcnt(0)+lgkmcnt(0) drain is the
// per-tile wait). Race-free: barrier at end of iter kt guarantees all waves
// finished reading buf[cur] (lgkm drained before their MFMAs) and all
// staging writes to buf^1 landed, before anyone overwrites buf[cur] in
// iter kt+1. LDS unpadded lane-linear (global_load_lds constraint); bank
// balance via XOR swizzle folded into the GLOBAL chunk choice:
// LDS[row][c] = G[row][c^(row&7)]  (verified 0 bank conflicts).
#define BM 128
#define BN 128
#define BK 64

enum { EP_BIAS = 0, EP_KV = 1, EP_SCALE = 2, EP_ACC = 3, EP_FINAL = 4 };

template <int MODE, bool ACCUM>
__global__ __launch_bounds__(256, 2)
void gemm_bt(const ushort* __restrict__ A, const ushort* __restrict__ B,
             void* __restrict__ C, void* __restrict__ C2,
             const float* __restrict__ aux,
             int M, int N, int K, int lda, int ldb, int ldc,
             long long sA, long long sB, long long sC, long long sAux,
             float scale) {
  __shared__ __align__(16) ushort As[2][BM * BK];
  __shared__ __align__(16) ushort Bs[2][BN * BK];
  const int b = blockIdx.z;
  const ushort* Ab = A + (long long)b * sA;
  const ushort* Bb = B + (long long)b * sB;
  const int m0 = blockIdx.y * BM;
  const int n0 = blockIdx.x * BN;
  const int t = threadIdx.x;
  const int lane = t & 63;
  const int w = t >> 6;
  const int wr = (w >> 1) * 64;
  const int wc = (w & 1) * 64;
  const int l15 = lane & 15;
  const int quad = lane >> 4;

  floatx4 acc[4][4];
#pragma unroll
  for (int i = 0; i < 4; i++)
#pragma unroll
    for (int j = 0; j < 4; j++)
#pragma unroll
      for (int r = 0; r < 4; r++) acc[i][j][r] = 0.f;

  // staging: 1024 chunks of 8 bf16 per 128x64 tile; wave w covers chunks
  // [w*256, w*256+256) via 4 lds-DMA instructions per operand.
  long long offA[4], offB[4];
  int loff[4];
#pragma unroll
  for (int i = 0; i < 4; i++) {
    const int q = w * 256 + i * 64 + lane;
    const int row = q >> 3;
    const int gk = ((q & 7) ^ (row & 7)) * 8;
    offA[i] = (long long)(m0 + row) * lda + gk;
    offB[i] = (long long)(n0 + row) * ldb + gk;
    loff[i] = (w * 256 + i * 64) * 8;  // wave-uniform LDS base (HW adds lane*16)
  }

  const int x7 = l15 & 7;
  const int nt = K / BK;

  // prologue: tile 0 -> buf 0
#pragma unroll
  for (int i = 0; i < 4; i++) async_cp16(Ab + offA[i], &As[0][loff[i]]);
#pragma unroll
  for (int i = 0; i < 4; i++) async_cp16(Bb + offB[i], &Bs[0][loff[i]]);
  __syncthreads();  // drains vmcnt -> tile 0 visible

  for (int kt = 0; kt < nt; ++kt) {
    const int cur = kt & 1;
    // issue next tile's staging first, so it flies under this tile's MFMA
    if (kt + 1 < nt) {
      const int k1 = (kt + 1) * BK;
#pragma unroll
      for (int i = 0; i < 4; i++)
        async_cp16(Ab + offA[i] + k1, &As[cur ^ 1][loff[i]]);
#pragma unroll
      for (int i = 0; i < 4; i++)
        async_cp16(Bb + offB[i] + k1, &Bs[cur ^ 1][loff[i]]);
    }
    const ushort* Asb = As[cur];
    const ushort* Bsb = Bs[cur];
#pragma unroll
    for (int s = 0; s < 2; s++) {
      const int col = ((s * 4 + quad) ^ x7) * 8;
      bf16x8 af[4], bfr[4];
#pragma unroll
      for (int mi = 0; mi < 4; mi++)
        af[mi] = *(const bf16x8*)(Asb + (wr + mi * 16 + l15) * BK + col);
#pragma unroll
      for (int ni = 0; ni < 4; ni++)
        bfr[ni] = *(const bf16x8*)(Bsb + (wc + ni * 16 + l15) * BK + col);
#pragma unroll
      for (int mi = 0; mi < 4; mi++)
#pragma unroll
        for (int ni = 0; ni < 4; ni++)
          acc[mi][ni] = __builtin_amdgcn_mfma_f32_16x16x32_bf16(
              af[mi], bfr[ni], acc[mi][ni], 0, 0, 0);
    }
    __syncthreads();  // one barrier per tile: drains stage writes + readers done
  }

#pragma unroll
  for (int mi = 0; mi < 4; mi++) {
#pragma unroll
    for (int ni = 0; ni < 4; ni++) {
      const int gm0 = m0 + wr + mi * 16 + quad * 4;
      const int gn = n0 + wc + ni * 16 + l15;
      if (MODE == EP_KV) {
        const float bias = aux[gn];
        if (gn < 512) {  // K half: normal layout (wave-uniform branch)
#pragma unroll
          for (int r = 0; r < 4; r++)
            ((ushort*)C)[(long long)(gm0 + r) * ldc + gn] =
                f2bf(acc[mi][ni][r] + bias);
        } else {  // V half: write transposed Vt[b][gn-512][token]
          const int b2 = gm0 >> 11;
          const int gmL = gm0 & 2047;
          ushort4 o;
          o.x = f2bf(acc[mi][ni][0] + bias);
          o.y = f2bf(acc[mi][ni][1] + bias);
          o.z = f2bf(acc[mi][ni][2] + bias);
          o.w = f2bf(acc[mi][ni][3] + bias);
          *(ushort4*)((ushort*)C2 + (long long)b2 * (512 * 2048) +
                      (long long)(gn - 512) * 2048 + gmL) = o;
        }
      } else {
        float bias = 0.f;
        if (MODE == EP_BIAS) bias = aux[gn];
#pragma unroll
        for (int r = 0; r < 4; r++) {
          const int gm = gm0 + r;
          const long long off = (long long)b * sC + (long long)gm * ldc + gn;
          float v = acc[mi][ni][r];
          if (MODE == EP_BIAS) {
            ((ushort*)C)[off] = f2bf(v + bias);
          } else if (MODE == EP_SCALE) {
            ((ushort*)C)[off] = f2bf(v * scale);
          } else if (MODE == EP_ACC) {
            if (ACCUM) v += bf2f(((ushort*)C)[off]);
            ((ushort*)C)[off] = f2bf(v);
          } else {  // EP_FINAL
            v += aux[(long long)b * sAux + (long long)gm * N + gn];
            ((float*)C)[off] = v;
          }
        }
      }
    }
  }
}

// ---------------- row softmax over 2048 bf16, in place ----------------
__global__ __launch_bounds__(256) void softmax_rows(ushort* __restrict__ S) {
  const long long row = blockIdx.x;
  ushort* p = S + (row << 11);
  const int t = threadIdx.x;
  const int lane = t & 63;
  const int w = t >> 6;

  uint4 raw = *(const uint4*)(p + (t << 3));
  const ushort* rs = (const ushort*)&raw;
  float v[8];
  for (int i = 0; i < 8; i++) v[i] = bf2f(rs[i]);

  float mx = v[0];
  for (int i = 1; i < 8; i++) mx = fmaxf(mx, v[i]);
  for (int off = 32; off; off >>= 1) mx = fmaxf(mx, __shfl_xor(mx, off, 64));
  __shared__ float redm[4];
  __shared__ float reds[4];
  if (lane == 0) redm[w] = mx;
  __syncthreads();
  mx = fmaxf(fmaxf(redm[0], redm[1]), fmaxf(redm[2], redm[3]));

  float s = 0.f;
  for (int i = 0; i < 8; i++) {
    v[i] = __expf(v[i] - mx);
    s += v[i];
  }
  for (int off = 32; off; off >>= 1) s += __shfl_xor(s, off, 64);
  if (lane == 0) reds[w] = s;
  __syncthreads();
  s = (reds[0] + reds[1]) + (reds[2] + reds[3]);
  const float inv = 1.0f / s;

  ushort o[8];
  for (int i = 0; i < 8; i++) o[i] = f2bf(v[i] * inv);
  *(uint4*)(p + (t << 3)) = *(const uint4*)o;
}

// ---------------- orchestration ----------------
extern "C" void kernel_launch(void* const* d_in, const int* in_sizes, int n_in,
                              void* d_out, int out_size, void* d_ws, size_t ws_size,
                              hipStream_t stream) {
  const float* Itime = (const float*)d_in[0];
  const float* Ispace = (const float*)d_in[1];
  const float* x0 = (const float*)d_in[2];
  const float* Wq = (const float*)d_in[3];
  const float* bq = (const float*)d_in[4];
  const float* Wk = (const float*)d_in[5];
  const float* bk = (const float*)d_in[6];
  const float* Wv = (const float*)d_in[7];
  const float* bv = (const float*)d_in[8];
  float* out = (float*)d_out;

  const long long SZX = 8388608;        // 8*2048*512
  const long long SZWP = 4LL * 1536 * 512;
  const long long SZS = 33554432;       // 8*2048*2048

  ushort* p = (ushort*)d_ws;
  ushort* Tb = p;   p += SZX;    // Itime bf16
  ushort* Sb = p;   p += SZX;    // Ispace bf16
  ushort* Wp = p;   p += SZWP;   // packed [4][1536][512] (Q,K,V rows)
  ushort* Qb = p;   p += SZX;    // Q proj [16384][512]
  ushort* Kb = p;   p += SZX;    // K proj [16384][512]
  ushort* Vt = p;   p += SZX;    // V^T [8][512][2048]
  ushort* Abf = p;  p += SZX;    // FTT + FTS
  ushort* Cbf = p;  p += SZX;    // FSS + FST
  ushort* Sc = p;   p += SZS;    // scores / probs (bf16)
  float* Bp = (float*)p;         // packed biases [4][1536] fp32 (24 KB)
  // total ws use ≈ 190.9 MB

  const dim3 blk(256);
  cvt_f32_bf16<<<dim3(8192), blk, 0, stream>>>(Itime, Tb, SZX);
  cvt_f32_bf16<<<dim3(8192), blk, 0, stream>>>(Ispace, Sb, SZX);
  pack_w<<<dim3(3072), blk, 0, stream>>>(Wq, Wk, Wv, Wp);
  pack_b<<<dim3(24), blk, 0, stream>>>(bq, bk, bv, Bp);

  const float scale = 0.04419417382415922f;  // 1/sqrt(512)

  auto attn = [&](const ushort* qs, const ushort* kvs, int pi,
                  ushort* dest, bool accum) {
    const ushort* Wqi = Wp + (long long)pi * 1536 * 512;
    const ushort* Wkvi = Wqi + 512 * 512;
    const float* Bqi = Bp + pi * 1536;
    // Q projection: [16384,512] = qs(16384x512) . WqT
    gemm_bt<EP_BIAS, false><<<dim3(4, 128, 1), blk, 0, stream>>>(
        qs, Wqi, Qb, nullptr, Bqi, 16384, 512, 512, 512, 512, 512,
        0, 0, 0, 0, 0.f);
    // K+V fused projection: K -> Kb (normal), V -> Vt (transposed per batch)
    gemm_bt<EP_KV, false><<<dim3(8, 128, 1), blk, 0, stream>>>(
        kvs, Wkvi, Kb, Vt, Bqi + 512, 16384, 1024, 512, 512, 512, 512,
        0, 0, 0, 0, 0.f);
    // scores: S = scale * Q K^T (per batch 2048x2048)
    gemm_bt<EP_SCALE, false><<<dim3(16, 16, 8), blk, 0, stream>>>(
        Qb, Kb, Sc, nullptr, nullptr, 2048, 2048, 512, 512, 512, 2048,
        1048576, 1048576, 4194304, 0, scale);
    softmax_rows<<<dim3(16384), blk, 0, stream>>>(Sc);
    // O (+)= P V : per batch M=2048, N=512, K=2048; B operand = Vt rows
    if (accum)
      gemm_bt<EP_ACC, true><<<dim3(4, 16, 8), blk, 0, stream>>>(
          Sc, Vt, dest, nullptr, nullptr, 2048, 512, 2048, 2048, 2048, 512,
          4194304, 1048576, 1048576, 0, 0.f);
    else
      gemm_bt<EP_ACC, false><<<dim3(4, 16, 8), blk, 0, stream>>>(
          Sc, Vt, dest, nullptr, nullptr, 2048, 512, 2048, 2048, 2048, 512,
          4194304, 1048576, 1048576, 0, 0.f);
  };

  attn(Tb, Tb, 0, Abf, false);   // FTT
  attn(Tb, Sb, 2, Abf, true);    // + FTS
  attn(Sb, Sb, 1, Cbf, false);   // FSS
  attn(Sb, Tb, 3, Cbf, true);    // + FST

  // out = Abf . Cbf^T + x_origin (fp32)
  gemm_bt<EP_FINAL, false><<<dim3(16, 16, 8), blk, 0, stream>>>(
      Abf, Cbf, out, nullptr, x0, 2048, 2048, 512, 512, 512, 2048,
      1048576, 1048576, 4194304, 4194304, 0.f);
}

// Round 3
// 934.335 us; speedup vs baseline: 1.1423x; 1.0804x over previous
//
#include <hip/hip_runtime.h>
#include <stdint.h>

typedef __bf16 bf16_t;
typedef bf16_t bf16x8 __attribute__((ext_vector_type(8)));
typedef float floatx4 __attribute__((ext_vector_type(4)));
typedef ushort ushortx8 __attribute__((ext_vector_type(8)));

__device__ __forceinline__ ushort f2bf(float f) {
  uint u = __float_as_uint(f);
  u += 0x7FFFu + ((u >> 16) & 1u);   // RNE; inputs finite/normal
  return (ushort)(u >> 16);
}
__device__ __forceinline__ float bf2f(ushort h) {
  return __uint_as_float(((uint)h) << 16);
}

// async 16B global->LDS DMA. LDS dest = wave-uniform base + lane*16.
__device__ __forceinline__ void async_cp16(const ushort* g, ushort* l) {
  __builtin_amdgcn_global_load_lds(
      (const __attribute__((address_space(1))) uint32_t*)g,
      (__attribute__((address_space(3))) uint32_t*)l, 16, 0, 0);
}

// ---------------- fp32 -> bf16 convert ----------------
__global__ __launch_bounds__(256) void cvt_f32_bf16(const float* __restrict__ in,
                                                    ushort* __restrict__ out,
                                                    long long n) {
  long long i = (((long long)blockIdx.x) * 256 + threadIdx.x) * 4;
  if (i + 3 < n) {
    float4 f = *(const float4*)(in + i);
    ushort4 o = make_ushort4(f2bf(f.x), f2bf(f.y), f2bf(f.z), f2bf(f.w));
    *(ushort4*)(out + i) = o;
  }
}

// ---- pack Wq/Wk/Wv (fp32) -> Wp[4][1536][512] bf16 (rows: Q,K,V stacked) ----
__global__ __launch_bounds__(256) void pack_w(const float* __restrict__ Wq,
                                              const float* __restrict__ Wk,
                                              const float* __restrict__ Wv,
                                              ushort* __restrict__ Wp) {
  long long t4 = (((long long)blockIdx.x) * 256 + threadIdx.x) * 4;  // < 4*1536*512
  const int k = (int)(t4 & 511);
  const int jr = (int)(t4 >> 9);       // 0..6143
  const int pi = jr / 1536;
  const int j = jr - pi * 1536;
  const int type = j >> 9;             // 0=Q 1=K 2=V
  const int jj = j & 511;
  const float* src = (type == 0 ? Wq : type == 1 ? Wk : Wv) +
                     ((long long)(pi * 512 + jj) << 9) + k;
  float4 f = *(const float4*)src;
  ushort4 o = make_ushort4(f2bf(f.x), f2bf(f.y), f2bf(f.z), f2bf(f.w));
  *(ushort4*)(Wp + t4) = o;
}

__global__ __launch_bounds__(256) void pack_b(const float* __restrict__ bq,
                                              const float* __restrict__ bk,
                                              const float* __restrict__ bv,
                                              float* __restrict__ Bp) {
  const int i = blockIdx.x * 256 + threadIdx.x;  // < 6144
  const int pi = i / 1536;
  const int j = i - pi * 1536;
  const int type = j >> 9;
  const int jj = j & 511;
  Bp[i] = (type == 0 ? bq : type == 1 ? bk : bv)[pi * 512 + jj];
}

// ---------------- BT-form bf16 MFMA GEMM ----------------
// C[m,n] = sum_k A[m,k]*B[n,k]; both operands k-contiguous (lda/ldb strides).
// BK=64, 128x128 tile, single-buffered 32 KiB LDS (proven round-0 engine;
// dbuf@64KiB regressed: blocks/CU 5->2). Bank balance via XOR swizzle folded
// into the GLOBAL chunk choice: LDS[row][c] = G[row][c^(row&7)].
// Epilogue: per-wave LDS transpose (stride-68 f32, reuses staging LDS) ->
// 128B/256B coalesced segments instead of 32B/64B scatter.
#define BM 128
#define BN 128
#define BK 64

enum { EP_QKV = 0, EP_SCALE = 2, EP_ACC = 3, EP_FINAL = 4 };

template <int MODE, bool ACCUM>
__global__ __launch_bounds__(256, 2)
void gemm_bt(const ushort* __restrict__ Aq, const ushort* __restrict__ Akv,
             const ushort* __restrict__ B,
             void* __restrict__ C, void* __restrict__ C2, void* __restrict__ C3,
             const float* __restrict__ aux,
             int M, int N, int K, int lda, int ldb, int ldc,
             long long sA, long long sB, long long sC, long long sAux,
             float scale) {
  __shared__ __align__(16) ushort sh[2][BM * BK];  // As=sh[0], Bs=sh[1]
  const int b = blockIdx.z;
  const int m0 = blockIdx.y * BM;
  const int n0 = blockIdx.x * BN;
  // EP_QKV: region 0 = Q (A=qs), 1 = K, 2 = V (A=kvs). Block-uniform.
  const int reg = (MODE == EP_QKV) ? (n0 >> 9) : 0;
  const ushort* Ab = ((MODE == EP_QKV && reg > 0) ? Akv : Aq) + (long long)b * sA;
  const ushort* Bb = B + (long long)b * sB;
  const int t = threadIdx.x;
  const int lane = t & 63;
  const int w = t >> 6;
  const int wr = (w >> 1) * 64;
  const int wc = (w & 1) * 64;
  const int l15 = lane & 15;
  const int quad = lane >> 4;

  floatx4 acc[4][4];
#pragma unroll
  for (int i = 0; i < 4; i++)
#pragma unroll
    for (int j = 0; j < 4; j++)
#pragma unroll
      for (int r = 0; r < 4; r++) acc[i][j][r] = 0.f;

  // staging: 1024 chunks of 8 bf16 per 128x64 tile; wave w covers chunks
  // [w*256, w*256+256) via 4 lds-DMA instructions per operand.
  long long offA[4], offB[4];
  int loff[4];
#pragma unroll
  for (int i = 0; i < 4; i++) {
    const int q = w * 256 + i * 64 + lane;
    const int row = q >> 3;
    const int gk = ((q & 7) ^ (row & 7)) * 8;
    offA[i] = (long long)(m0 + row) * lda + gk;
    offB[i] = (long long)(n0 + row) * ldb + gk;
    loff[i] = (w * 256 + i * 64) * 8;  // wave-uniform LDS base (HW adds lane*16)
  }

  const int x7 = l15 & 7;
  for (int k0 = 0; k0 < K; k0 += BK) {
    __syncthreads();  // prev iter's ds_reads done before overwrite
#pragma unroll
    for (int i = 0; i < 4; i++) async_cp16(Ab + offA[i] + k0, &sh[0][loff[i]]);
#pragma unroll
    for (int i = 0; i < 4; i++) async_cp16(Bb + offB[i] + k0, &sh[1][loff[i]]);
    __syncthreads();  // drains vmcnt -> staging visible

#pragma unroll
    for (int s = 0; s < 2; s++) {
      const int col = ((s * 4 + quad) ^ x7) * 8;
      bf16x8 af[4], bfr[4];
#pragma unroll
      for (int mi = 0; mi < 4; mi++)
        af[mi] = *(const bf16x8*)(&sh[0][0] + (wr + mi * 16 + l15) * BK + col);
#pragma unroll
      for (int ni = 0; ni < 4; ni++)
        bfr[ni] = *(const bf16x8*)(&sh[1][0] + (wc + ni * 16 + l15) * BK + col);
#pragma unroll
      for (int mi = 0; mi < 4; mi++)
#pragma unroll
        for (int ni = 0; ni < 4; ni++)
          acc[mi][ni] = __builtin_amdgcn_mfma_f32_16x16x32_bf16(
              af[mi], bfr[ni], acc[mi][ni], 0, 0, 0);
    }
  }

  // ---------------- epilogue ----------------
  // Per-column bias (QKV only); col for lane = n0+wc+ni*16+l15.
  float biasv[4];
  if (MODE == EP_QKV) {
#pragma unroll
    for (int ni = 0; ni < 4; ni++) biasv[ni] = aux[n0 + wc + ni * 16 + l15];
  }

  if (MODE == EP_QKV && reg == 2) {
    // V region: write transposed Vt[b2][vcol][token] (token = gm, ushort4 runs)
#pragma unroll
    for (int mi = 0; mi < 4; mi++) {
#pragma unroll
      for (int ni = 0; ni < 4; ni++) {
        const int gm0 = m0 + wr + mi * 16 + quad * 4;
        const int gn = n0 + wc + ni * 16 + l15;
        const float bias = biasv[ni];
        const int b2 = gm0 >> 11;
        const int gmL = gm0 & 2047;
        ushort4 o;
        o.x = f2bf(acc[mi][ni][0] + bias);
        o.y = f2bf(acc[mi][ni][1] + bias);
        o.z = f2bf(acc[mi][ni][2] + bias);
        o.w = f2bf(acc[mi][ni][3] + bias);
        *(ushort4*)((ushort*)C2 + (long long)b2 * (512 * 2048) +
                    (long long)(gn - 1024) * 2048 + gmL) = o;
      }
    }
    return;
  }

  // Transposing epilogue: per wave a 16x64 f32 tile (stride 68, 4352B) in the
  // staging LDS (4 waves * 4352 = 17408B <= 32768B). 4 passes (one per mi).
  __syncthreads();  // all waves done reading staging LDS
  float* shf = (float*)&sh[0][0];
  const int wbase = w * 1088;  // floats

#pragma unroll
  for (int mi = 0; mi < 4; mi++) {
    // -- write phase: 16 scalar ds_writes (2-way bank alias max: free)
#pragma unroll
    for (int ni = 0; ni < 4; ni++) {
#pragma unroll
      for (int r = 0; r < 4; r++) {
        float v = acc[mi][ni][r];
        if (MODE == EP_QKV) v += biasv[ni];
        if (MODE == EP_SCALE) v *= scale;
        shf[wbase + (quad * 4 + r) * 68 + ni * 16 + l15] = v;
      }
    }
    asm volatile("s_waitcnt lgkmcnt(0)" ::: "memory");
    __builtin_amdgcn_sched_barrier(0);

    const int gmb = m0 + wr + mi * 16;
    if (MODE == EP_FINAL) {
      // fp32 out: 4 sub-iters of (4 rows x 16 lanes x float4) = 256B segments
#pragma unroll
      for (int j = 0; j < 4; j++) {
        const int rr = j * 4 + (lane >> 4);
        const int c0 = (lane & 15) * 4;
        float4 f = *(const float4*)&shf[wbase + rr * 68 + c0];
        const int gm = gmb + rr;
        const int gn = n0 + wc + c0;
        float4 x = *(const float4*)(aux + (long long)b * sAux +
                                    (long long)gm * N + gn);
        f.x += x.x; f.y += x.y; f.z += x.z; f.w += x.w;
        *(float4*)((float*)C + (long long)b * sC + (long long)gm * ldc + gn) = f;
      }
    } else {
      // bf16 out: 2 sub-iters of (8 rows x 8 lanes x ushort8) = 128B segments
#pragma unroll
      for (int j = 0; j < 2; j++) {
        const int rr = j * 8 + (lane >> 3);
        const int c0 = (lane & 7) * 8;
        float4 f0 = *(const float4*)&shf[wbase + rr * 68 + c0];
        float4 f1 = *(const float4*)&shf[wbase + rr * 68 + c0 + 4];
        const int gm = gmb + rr;
        const int gn = n0 + wc + c0;
        float vv[8] = {f0.x, f0.y, f0.z, f0.w, f1.x, f1.y, f1.z, f1.w};
        ushort* base;
        long long off;
        if (MODE == EP_QKV) {
          if (reg == 0) { base = (ushort*)C;  off = (long long)gm * ldc + gn; }
          else          { base = (ushort*)C3; off = (long long)gm * ldc + (gn - 512); }
        } else {
          base = (ushort*)C;
          off = (long long)b * sC + (long long)gm * ldc + gn;
        }
        if (MODE == EP_ACC && ACCUM) {
          ushortx8 old = *(const ushortx8*)(base + off);
#pragma unroll
          for (int e = 0; e < 8; e++) vv[e] += bf2f(old[e]);
        }
        ushortx8 o;
#pragma unroll
        for (int e = 0; e < 8; e++) o[e] = f2bf(vv[e]);
        *(ushortx8*)(base + off) = o;
      }
    }
  }
}

// ---------------- row softmax over 2048 bf16, in place ----------------
__global__ __launch_bounds__(256) void softmax_rows(ushort* __restrict__ S) {
  const long long row = blockIdx.x;
  ushort* p = S + (row << 11);
  const int t = threadIdx.x;
  const int lane = t & 63;
  const int w = t >> 6;

  uint4 raw = *(const uint4*)(p + (t << 3));
  const ushort* rs = (const ushort*)&raw;
  float v[8];
  for (int i = 0; i < 8; i++) v[i] = bf2f(rs[i]);

  float mx = v[0];
  for (int i = 1; i < 8; i++) mx = fmaxf(mx, v[i]);
  for (int off = 32; off; off >>= 1) mx = fmaxf(mx, __shfl_xor(mx, off, 64));
  __shared__ float redm[4];
  __shared__ float reds[4];
  if (lane == 0) redm[w] = mx;
  __syncthreads();
  mx = fmaxf(fmaxf(redm[0], redm[1]), fmaxf(redm[2], redm[3]));

  float s = 0.f;
  for (int i = 0; i < 8; i++) {
    v[i] = __expf(v[i] - mx);
    s += v[i];
  }
  for (int off = 32; off; off >>= 1) s += __shfl_xor(s, off, 64);
  if (lane == 0) reds[w] = s;
  __syncthreads();
  s = (reds[0] + reds[1]) + (reds[2] + reds[3]);
  const float inv = 1.0f / s;

  ushort o[8];
  for (int i = 0; i < 8; i++) o[i] = f2bf(v[i] * inv);
  *(uint4*)(p + (t << 3)) = *(const uint4*)o;
}

// ---------------- orchestration ----------------
extern "C" void kernel_launch(void* const* d_in, const int* in_sizes, int n_in,
                              void* d_out, int out_size, void* d_ws, size_t ws_size,
                              hipStream_t stream) {
  const float* Itime = (const float*)d_in[0];
  const float* Ispace = (const float*)d_in[1];
  const float* x0 = (const float*)d_in[2];
  const float* Wq = (const float*)d_in[3];
  const float* bq = (const float*)d_in[4];
  const float* Wk = (const float*)d_in[5];
  const float* bk = (const float*)d_in[6];
  const float* Wv = (const float*)d_in[7];
  const float* bv = (const float*)d_in[8];
  float* out = (float*)d_out;

  const long long SZX = 8388608;        // 8*2048*512
  const long long SZWP = 4LL * 1536 * 512;
  const long long SZS = 33554432;       // 8*2048*2048

  ushort* p = (ushort*)d_ws;
  ushort* Tb = p;   p += SZX;    // Itime bf16
  ushort* Sb = p;   p += SZX;    // Ispace bf16
  ushort* Wp = p;   p += SZWP;   // packed [4][1536][512] (Q,K,V rows)
  ushort* Qb = p;   p += SZX;    // Q proj [16384][512]
  ushort* Kb = p;   p += SZX;    // K proj [16384][512]
  ushort* Vt = p;   p += SZX;    // V^T [8][512][2048]
  ushort* Abf = p;  p += SZX;    // FTT + FTS
  ushort* Cbf = p;  p += SZX;    // FSS + FST
  ushort* Sc = p;   p += SZS;    // scores / probs (bf16)
  float* Bp = (float*)p;         // packed biases [4][1536] fp32 (24 KB)
  // total ws use ≈ 190.9 MB

  const dim3 blk(256);
  cvt_f32_bf16<<<dim3(8192), blk, 0, stream>>>(Itime, Tb, SZX);
  cvt_f32_bf16<<<dim3(8192), blk, 0, stream>>>(Ispace, Sb, SZX);
  pack_w<<<dim3(3072), blk, 0, stream>>>(Wq, Wk, Wv, Wp);
  pack_b<<<dim3(24), blk, 0, stream>>>(bq, bk, bv, Bp);

  const float scale = 0.04419417382415922f;  // 1/sqrt(512)

  auto attn = [&](const ushort* qs, const ushort* kvs, int pi,
                  ushort* dest, bool accum) {
    const ushort* Wqi = Wp + (long long)pi * 1536 * 512;
    const float* Bqi = Bp + pi * 1536;
    // Fused Q+K+V projection: [16384,1536]; region (Q/K/V) block-uniform.
    // Q -> Qb, K -> Kb, V -> Vt (transposed per batch).
    gemm_bt<EP_QKV, false><<<dim3(12, 128, 1), blk, 0, stream>>>(
        qs, kvs, Wqi, Qb, Vt, Kb, Bqi, 16384, 1536, 512, 512, 512, 512,
        0, 0, 0, 0, 0.f);
    // scores: S = scale * Q K^T (per batch 2048x2048)
    gemm_bt<EP_SCALE, false><<<dim3(16, 16, 8), blk, 0, stream>>>(
        Qb, Qb, Kb, Sc, nullptr, nullptr, nullptr, 2048, 2048, 512, 512, 512,
        2048, 1048576, 1048576, 4194304, 0, scale);
    softmax_rows<<<dim3(16384), blk, 0, stream>>>(Sc);
    // O (+)= P V : per batch M=2048, N=512, K=2048; B operand = Vt rows
    if (accum)
      gemm_bt<EP_ACC, true><<<dim3(4, 16, 8), blk, 0, stream>>>(
          Sc, Sc, Vt, dest, nullptr, nullptr, nullptr, 2048, 512, 2048, 2048,
          2048, 512, 4194304, 1048576, 1048576, 0, 0.f);
    else
      gemm_bt<EP_ACC, false><<<dim3(4, 16, 8), blk, 0, stream>>>(
          Sc, Sc, Vt, dest, nullptr, nullptr, nullptr, 2048, 512, 2048, 2048,
          2048, 512, 4194304, 1048576, 1048576, 0, 0.f);
  };

  attn(Tb, Tb, 0, Abf, false);   // FTT
  attn(Tb, Sb, 2, Abf, true);    // + FTS
  attn(Sb, Sb, 1, Cbf, false);   // FSS
  attn(Sb, Tb, 3, Cbf, true);    // + FST

  // out = Abf . Cbf^T + x_origin (fp32)
  gemm_bt<EP_FINAL, false><<<dim3(16, 16, 8), blk, 0, stream>>>(
      Abf, Abf, Cbf, out, nullptr, nullptr, x0, 2048, 2048, 512, 512, 512,
      2048, 1048576, 1048576, 4194304, 4194304, 0.f);
}